// Round 10
// baseline (38.787 us; speedup 1.0000x reference)
//
#include <hip/hip_runtime.h>

constexpr int GRID_SZ = 5;
constexpr int N_CTRL  = 25;
constexpr int IMG_H   = 256;
constexpr int IMG_W   = 192;
constexpr int BATCH   = 64;
constexpr int BCHUNK  = 4;    // batches per block; ALL prefetched via asm loads
constexpr int PLANE   = IMG_H * IMG_W;
constexpr int PIX_BLOCKS = PLANE / 256;             // 192
constexpr int NWG = PIX_BLOCKS * (BATCH / BCHUNK);  // 3072, divisible by 8
constexpr float RBF_SCALE = 10.0f;
constexpr float OFF_SCALE = 0.3f;

typedef float vf2 __attribute__((ext_vector_type(2)));

__global__ __launch_bounds__(256) void tps_warp_kernel(
    const float* __restrict__ cloth,   // (64,3,256,192)
    const float* __restrict__ theta,   // (64,50)
    float* __restrict__ out)           // (64,3,256,192)
{
    // XCD-contiguous swizzle (keeps HBM FETCH at compulsory ~17 MB).
    const int flat = blockIdx.x;
    const int wg   = (flat & 7) * (NWG / 8) + (flat >> 3);
    const int pb   = wg % PIX_BLOCKS;
    const int bc   = wg / PIX_BLOCKS;
    const int b0   = bc * BCHUNK;

    const int pix = pb * 256 + threadIdx.x;
    const int hh = pix / IMG_W;
    const int ww = pix - hh * IMG_W;
    const float mx = -1.0f + (2.0f / (IMG_W - 1)) * (float)ww;
    const float my = -1.0f + (2.0f / (IMG_H - 1)) * (float)hh;

    // separable RBF basis: 10 exps + 25 muls; OFF_SCALE folded in.
    float ex[GRID_SZ], ey[GRID_SZ];
#pragma unroll
    for (int k = 0; k < GRID_SZ; ++k) {
        const float c = -0.9f + 0.45f * (float)k;
        const float dx = mx - c;
        const float dy = my - c;
        ex[k] = __expf(-dx * dx * RBF_SCALE);
        ey[k] = __expf(-dy * dy * RBF_SCALE);
    }
    float wgt[N_CTRL];
#pragma unroll
    for (int n = 0; n < N_CTRL; ++n)
        wgt[n] = OFF_SCALE * ex[n % GRID_SZ] * ey[n / GRID_SZ];

    // ---- phase A: sample coords per batch (theta via SGPR s_loads, no LDS)
    float sxp[BCHUNK], syp[BCHUNK];
#pragma unroll
    for (int bi = 0; bi < BCHUNK; ++bi) {
        const float* __restrict__ th = theta + (size_t)(b0 + bi) * (2 * N_CTRL);
        float ox = 0.0f, oy = 0.0f;
#pragma unroll
        for (int n = 0; n < N_CTRL; ++n) {
            ox = fmaf(th[2 * n + 0], wgt[n], ox);
            oy = fmaf(th[2 * n + 1], wgt[n], oy);
        }
        const float gx = fminf(fmaxf(mx + ox, -1.0f), 1.0f);
        const float gy = fminf(fmaxf(my + oy, -1.0f), 1.0f);
        sxp[bi] = (gx + 1.0f) * (0.5f * (float)(IMG_W - 1));  // in [0, W-1]
        syp[bi] = (gy + 1.0f) * (0.5f * (float)(IMG_H - 1));  // in [0, H-1]
    }

    const size_t img_stride = (size_t)3 * PLANE;
    const float* imgb = cloth + (size_t)b0 * img_stride;
    float*       outb = out   + (size_t)b0 * img_stride + pix;

    // ---- phase B: issue ALL 24 gathers as VOLATILE asm loads (cannot be
    // deleted, reordered among themselves, or sunk past the waitcnt below).
    // R8/R9 lesson: sched_barrier + empty-asm pins both failed to stop the
    // compiler from re-serializing (VGPR stayed 36) — so the loads must be
    // issued by instructions the compiler cannot move at all.
    vf2 v[BCHUNK][6];     // [batch][ch*2 + row]
#pragma unroll
    for (int bi = 0; bi < BCHUNK; ++bi) {
        const int x0 = min((int)sxp[bi], IMG_W - 2);
        const int y0 = min((int)syp[bi], IMG_H - 2);
        const int base = y0 * IMG_W + x0;
        const float* img = imgb + (size_t)bi * img_stride;
#pragma unroll
        for (int ch = 0; ch < 3; ++ch) {
            const float* p0 = img + ch * PLANE + base;
            const float* p1 = p0 + IMG_W;
            asm volatile("global_load_dwordx2 %0, %1, off"
                         : "=v"(v[bi][ch * 2 + 0]) : "v"(p0));
            asm volatile("global_load_dwordx2 %0, %1, off"
                         : "=v"(v[bi][ch * 2 + 1]) : "v"(p1));
        }
    }

    // The wait IS the pin: this asm both drains vmcnt and redefines ("+v")
    // every loaded value, so all loads must precede it (def) and every blend
    // must follow it (use). Airtight at IR and machine level (rule #18).
    asm volatile("s_waitcnt vmcnt(0)"
                 : "+v"(v[0][0]), "+v"(v[0][1]), "+v"(v[0][2]),
                   "+v"(v[0][3]), "+v"(v[0][4]), "+v"(v[0][5]),
                   "+v"(v[1][0]), "+v"(v[1][1]), "+v"(v[1][2]),
                   "+v"(v[1][3]), "+v"(v[1][4]), "+v"(v[1][5]),
                   "+v"(v[2][0]), "+v"(v[2][1]), "+v"(v[2][2]),
                   "+v"(v[2][3]), "+v"(v[2][4]), "+v"(v[2][5]),
                   "+v"(v[3][0]), "+v"(v[3][1]), "+v"(v[3][2]),
                   "+v"(v[3][3]), "+v"(v[3][4]), "+v"(v[3][5]));
    __builtin_amdgcn_sched_barrier(0);

    // ---- phase C: blend all batches into registers
    float res[BCHUNK][3];
#pragma unroll
    for (int bi = 0; bi < BCHUNK; ++bi) {
        const float x = sxp[bi];
        const float y = syp[bi];
        const float wx = x - (float)min((int)x, IMG_W - 2);
        const float wy = y - (float)min((int)y, IMG_H - 2);
#pragma unroll
        for (int ch = 0; ch < 3; ++ch) {
            const vf2 r0 = v[bi][ch * 2 + 0];
            const vf2 r1 = v[bi][ch * 2 + 1];
            const float top = fmaf(wx, r0[1] - r0[0], r0[0]);
            const float bot = fmaf(wx, r1[1] - r1[0], r1[0]);
            res[bi][ch]     = fmaf(wy, bot - top, top);
        }
    }

    // ---- phase D: all stores at the end (nothing waits on them; NT keeps
    // 37 MB of write traffic out of the L2).
#pragma unroll
    for (int bi = 0; bi < BCHUNK; ++bi) {
        float* op = outb + (size_t)bi * img_stride;
#pragma unroll
        for (int ch = 0; ch < 3; ++ch)
            __builtin_nontemporal_store(res[bi][ch], op + ch * PLANE);
    }
}

extern "C" void kernel_launch(void* const* d_in, const int* in_sizes, int n_in,
                              void* d_out, int out_size, void* d_ws, size_t ws_size,
                              hipStream_t stream) {
    const float* cloth = (const float*)d_in[0];
    const float* theta = (const float*)d_in[1];
    float* out = (float*)d_out;

    tps_warp_kernel<<<dim3(NWG), dim3(256), 0, stream>>>(cloth, theta, out);
}

// Round 11
// 37.932 us; speedup vs baseline: 1.0226x; 1.0226x over previous
//
#include <hip/hip_runtime.h>

constexpr int GRID_SZ = 5;
constexpr int N_CTRL  = 25;
constexpr int IMG_H   = 256;
constexpr int IMG_W   = 192;
constexpr int BATCH   = 64;
constexpr int BCHUNK  = 4;    // batches per block; 2-batch-deep counted-vmcnt pipeline
constexpr int PLANE   = IMG_H * IMG_W;
constexpr int PIX_BLOCKS = PLANE / 256;             // 192
constexpr int NWG = PIX_BLOCKS * (BATCH / BCHUNK);  // 3072, divisible by 8
constexpr float RBF_SCALE = 10.0f;
constexpr float OFF_SCALE = 0.3f;

typedef float vf2 __attribute__((ext_vector_type(2)));

__global__ __launch_bounds__(256) void tps_warp_kernel(
    const float* __restrict__ cloth,   // (64,3,256,192)
    const float* __restrict__ theta,   // (64,50)
    float* __restrict__ out)           // (64,3,256,192)
{
    // XCD-contiguous swizzle (keeps HBM FETCH at compulsory ~17 MB).
    const int flat = blockIdx.x;
    const int wg   = (flat & 7) * (NWG / 8) + (flat >> 3);
    const int pb   = wg % PIX_BLOCKS;
    const int bc   = wg / PIX_BLOCKS;
    const int b0   = bc * BCHUNK;

    const int pix = pb * 256 + threadIdx.x;
    const int hh = pix / IMG_W;
    const int ww = pix - hh * IMG_W;
    const float mx = -1.0f + (2.0f / (IMG_W - 1)) * (float)ww;
    const float my = -1.0f + (2.0f / (IMG_H - 1)) * (float)hh;

    // separable RBF basis: 10 exps + 25 muls; OFF_SCALE folded in.
    float ex[GRID_SZ], ey[GRID_SZ];
#pragma unroll
    for (int k = 0; k < GRID_SZ; ++k) {
        const float c = -0.9f + 0.45f * (float)k;
        const float dx = mx - c;
        const float dy = my - c;
        ex[k] = __expf(-dx * dx * RBF_SCALE);
        ey[k] = __expf(-dy * dy * RBF_SCALE);
    }
    float wgt[N_CTRL];
#pragma unroll
    for (int n = 0; n < N_CTRL; ++n)
        wgt[n] = OFF_SCALE * ex[n % GRID_SZ] * ey[n / GRID_SZ];

    // ---- phase A: sample coords per batch (theta via SGPR s_loads, no LDS)
    float sxp[BCHUNK], syp[BCHUNK];
#pragma unroll
    for (int bi = 0; bi < BCHUNK; ++bi) {
        const float* __restrict__ th = theta + (size_t)(b0 + bi) * (2 * N_CTRL);
        float ox = 0.0f, oy = 0.0f;
#pragma unroll
        for (int n = 0; n < N_CTRL; ++n) {
            ox = fmaf(th[2 * n + 0], wgt[n], ox);
            oy = fmaf(th[2 * n + 1], wgt[n], oy);
        }
        const float gx = fminf(fmaxf(mx + ox, -1.0f), 1.0f);
        const float gy = fminf(fmaxf(my + oy, -1.0f), 1.0f);
        sxp[bi] = (gx + 1.0f) * (0.5f * (float)(IMG_W - 1));  // in [0, W-1]
        syp[bi] = (gy + 1.0f) * (0.5f * (float)(IMG_H - 1));  // in [0, H-1]
    }

    const size_t img_stride = (size_t)3 * PLANE;
    const float* imgb = cloth + (size_t)b0 * img_stride;
    float*       outb = out   + (size_t)b0 * img_stride + pix;

    // ---- phase B: 2-batch-deep counted-vmcnt pipeline.
    // R7-R10 lesson: depth-24 prefetch needs a 48+ VGPR live-set the
    // allocator won't grant (it spills -> re-serializes). Depth-12 (2
    // batches) fits; volatile asm loads can't sink, and each batch's
    // consumes are pinned by a counted s_waitcnt whose "+v" operands are
    // that batch's values (T4: never drain vmcnt to 0 mid-loop).
    vf2 v[BCHUNK][6];     // only 2 batches live at a time
    float res[BCHUNK][3];

    auto ld6 = [&](int bi) {
        const int x0 = min((int)sxp[bi], IMG_W - 2);
        const int y0 = min((int)syp[bi], IMG_H - 2);
        const int base = y0 * IMG_W + x0;
        const float* img = imgb + (size_t)bi * img_stride;
#pragma unroll
        for (int ch = 0; ch < 3; ++ch) {
            const float* p0 = img + ch * PLANE + base;
            const float* p1 = p0 + IMG_W;
            asm volatile("global_load_dwordx2 %0, %1, off"
                         : "=v"(v[bi][ch * 2 + 0]) : "v"(p0));
            asm volatile("global_load_dwordx2 %0, %1, off"
                         : "=v"(v[bi][ch * 2 + 1]) : "v"(p1));
        }
    };

    auto blend = [&](int bi) {
        const float x = sxp[bi];
        const float y = syp[bi];
        const float wx = x - (float)min((int)x, IMG_W - 2);
        const float wy = y - (float)min((int)y, IMG_H - 2);
#pragma unroll
        for (int ch = 0; ch < 3; ++ch) {
            const vf2 r0 = v[bi][ch * 2 + 0];
            const vf2 r1 = v[bi][ch * 2 + 1];
            const float top = fmaf(wx, r0[1] - r0[0], r0[0]);
            const float bot = fmaf(wx, r1[1] - r1[0], r1[0]);
            res[bi][ch]     = fmaf(wy, bot - top, top);
        }
    };

#define PIN_WAIT(bi, N)                                                    \
    asm volatile("s_waitcnt vmcnt(" #N ")"                                 \
                 : "+v"(v[bi][0]), "+v"(v[bi][1]), "+v"(v[bi][2]),         \
                   "+v"(v[bi][3]), "+v"(v[bi][4]), "+v"(v[bi][5]))

    ld6(0);
    ld6(1);
    PIN_WAIT(0, 6);  blend(0);   // batch0 done; batch1's 6 still in flight
    ld6(2);
    PIN_WAIT(1, 6);  blend(1);   // batch1 done; batch2's 6 in flight
    ld6(3);
    PIN_WAIT(2, 6);  blend(2);   // batch2 done; batch3's 6 in flight
    PIN_WAIT(3, 0);  blend(3);   // final drain
#undef PIN_WAIT

    // ---- phase C: all stores at the end (nothing waits on them; NT keeps
    // 37 MB of write traffic out of the L2).
#pragma unroll
    for (int bi = 0; bi < BCHUNK; ++bi) {
        float* op = outb + (size_t)bi * img_stride;
#pragma unroll
        for (int ch = 0; ch < 3; ++ch)
            __builtin_nontemporal_store(res[bi][ch], op + ch * PLANE);
    }
}

extern "C" void kernel_launch(void* const* d_in, const int* in_sizes, int n_in,
                              void* d_out, int out_size, void* d_ws, size_t ws_size,
                              hipStream_t stream) {
    const float* cloth = (const float*)d_in[0];
    const float* theta = (const float*)d_in[1];
    float* out = (float*)d_out;

    tps_warp_kernel<<<dim3(NWG), dim3(256), 0, stream>>>(cloth, theta, out);
}

// Round 12
// 36.439 us; speedup vs baseline: 1.0644x; 1.0410x over previous
//
#include <hip/hip_runtime.h>

constexpr int GRID_SZ = 5;
constexpr int N_CTRL  = 25;
constexpr int IMG_H   = 256;
constexpr int IMG_W   = 192;
constexpr int BATCH   = 64;
constexpr int BCHUNK  = 4;    // batches per block; 2-batch-deep counted-vmcnt pipeline
constexpr int PLANE   = IMG_H * IMG_W;
constexpr int PIX_BLOCKS = PLANE / 256;             // 192
constexpr int NWG = PIX_BLOCKS * (BATCH / BCHUNK);  // 3072, divisible by 8
constexpr float RBF_SCALE = 10.0f;
constexpr float OFF_SCALE = 0.3f;

typedef float vf2 __attribute__((ext_vector_type(2)));

__device__ __forceinline__ float bilin(float wx, float wy, vf2 r0, vf2 r1) {
    const float top = fmaf(wx, r0[1] - r0[0], r0[0]);
    const float bot = fmaf(wx, r1[1] - r1[0], r1[0]);
    return fmaf(wy, bot - top, top);
}

// 6 volatile gather loads for one batch: 3 channel-pointers, row-pair via
// offset:768 (= IMG_W floats). Volatile asm: cannot be deleted/reordered/sunk.
#define LOAD6(PBASE, VA0, VA1, VB0, VB1, VC0, VC1) do {                        \
    const float* p0_ = (PBASE);                                                \
    const float* p1_ = p0_ + PLANE;                                            \
    const float* p2_ = p1_ + PLANE;                                            \
    asm volatile("global_load_dwordx2 %0, %1, off"            : "=v"(VA0) : "v"(p0_)); \
    asm volatile("global_load_dwordx2 %0, %1, off offset:768" : "=v"(VA1) : "v"(p0_)); \
    asm volatile("global_load_dwordx2 %0, %1, off"            : "=v"(VB0) : "v"(p1_)); \
    asm volatile("global_load_dwordx2 %0, %1, off offset:768" : "=v"(VB1) : "v"(p1_)); \
    asm volatile("global_load_dwordx2 %0, %1, off"            : "=v"(VC0) : "v"(p2_)); \
    asm volatile("global_load_dwordx2 %0, %1, off offset:768" : "=v"(VC1) : "v"(p2_)); \
} while (0)

// Counted wait that PINS one batch's values: they are inputs AND outputs, so
// all its loads must precede (def) and all its blends must follow (use).
#define WAIT6(N, V0, V1, V2, V3, V4, V5)                                       \
    asm volatile("s_waitcnt vmcnt(" #N ")"                                     \
                 : "+v"(V0), "+v"(V1), "+v"(V2), "+v"(V3), "+v"(V4), "+v"(V5))

__global__ __launch_bounds__(256, 4) void tps_warp_kernel(
    const float* __restrict__ cloth,   // (64,3,256,192)
    const float* __restrict__ theta,   // (64,50)
    float* __restrict__ out)           // (64,3,256,192)
{
    // XCD-contiguous swizzle (keeps HBM FETCH at compulsory ~17 MB).
    const int flat = blockIdx.x;
    const int wg   = (flat & 7) * (NWG / 8) + (flat >> 3);
    const int pb   = wg % PIX_BLOCKS;
    const int bc   = wg / PIX_BLOCKS;
    const int b0   = bc * BCHUNK;

    const int pix = pb * 256 + threadIdx.x;
    const int hh = pix / IMG_W;
    const int ww = pix - hh * IMG_W;
    const float mx = -1.0f + (2.0f / (IMG_W - 1)) * (float)ww;
    const float my = -1.0f + (2.0f / (IMG_H - 1)) * (float)hh;

    // Separable RBF basis — ALL NAMED SCALARS (R7-R11 lesson: any aggregate in
    // the hot path risks scratch demotion; VGPR_Count 24-40 proved arrays
    // never lived in registers).
#define RB(d) __expf(-(d) * (d) * RBF_SCALE)
    const float ex0 = RB(mx + 0.90f), ex1 = RB(mx + 0.45f), ex2 = RB(mx),
                ex3 = RB(mx - 0.45f), ex4 = RB(mx - 0.90f);
    const float ey0 = RB(my + 0.90f), ey1 = RB(my + 0.45f), ey2 = RB(my),
                ey3 = RB(my - 0.45f), ey4 = RB(my - 0.90f);
#undef RB

    // ---- phase A: 4 batches' offset accumulation in one pass, named accums.
    const float* t0 = theta + (size_t)(b0 + 0) * (2 * N_CTRL);
    const float* t1 = theta + (size_t)(b0 + 1) * (2 * N_CTRL);
    const float* t2 = theta + (size_t)(b0 + 2) * (2 * N_CTRL);
    const float* t3 = theta + (size_t)(b0 + 3) * (2 * N_CTRL);
    float ox0 = 0, oy0 = 0, ox1 = 0, oy1 = 0, ox2 = 0, oy2 = 0, ox3 = 0, oy3 = 0;
#define TERM(n, EX, EY) {                                                      \
    const float w_ = OFF_SCALE * (EX) * (EY);                                  \
    ox0 = fmaf(t0[2*(n)], w_, ox0); oy0 = fmaf(t0[2*(n)+1], w_, oy0);          \
    ox1 = fmaf(t1[2*(n)], w_, ox1); oy1 = fmaf(t1[2*(n)+1], w_, oy1);          \
    ox2 = fmaf(t2[2*(n)], w_, ox2); oy2 = fmaf(t2[2*(n)+1], w_, oy2);          \
    ox3 = fmaf(t3[2*(n)], w_, ox3); oy3 = fmaf(t3[2*(n)+1], w_, oy3); }
    TERM( 0, ex0, ey0) TERM( 1, ex1, ey0) TERM( 2, ex2, ey0) TERM( 3, ex3, ey0) TERM( 4, ex4, ey0)
    TERM( 5, ex0, ey1) TERM( 6, ex1, ey1) TERM( 7, ex2, ey1) TERM( 8, ex3, ey1) TERM( 9, ex4, ey1)
    TERM(10, ex0, ey2) TERM(11, ex1, ey2) TERM(12, ex2, ey2) TERM(13, ex3, ey2) TERM(14, ex4, ey2)
    TERM(15, ex0, ey3) TERM(16, ex1, ey3) TERM(17, ex2, ey3) TERM(18, ex3, ey3) TERM(19, ex4, ey3)
    TERM(20, ex0, ey4) TERM(21, ex1, ey4) TERM(22, ex2, ey4) TERM(23, ex3, ey4) TERM(24, ex4, ey4)
#undef TERM

#define COORD(OX, OY, SX, SY)                                                  \
    const float SX = (fminf(fmaxf(mx + (OX), -1.0f), 1.0f) + 1.0f) * (0.5f * (float)(IMG_W - 1)); \
    const float SY = (fminf(fmaxf(my + (OY), -1.0f), 1.0f) + 1.0f) * (0.5f * (float)(IMG_H - 1));
    COORD(ox0, oy0, sx0, sy0)
    COORD(ox1, oy1, sx1, sy1)
    COORD(ox2, oy2, sx2, sy2)
    COORD(ox3, oy3, sx3, sy3)
#undef COORD

    const size_t img_stride = (size_t)3 * PLANE;
    const float* imgb = cloth + (size_t)b0 * img_stride;
    float*       outb = out   + (size_t)b0 * img_stride + pix;

#define PBASE(B, SX, SY) (imgb + (size_t)(B) * img_stride +                    \
    (size_t)(min((int)(SY), IMG_H - 2) * IMG_W + min((int)(SX), IMG_W - 2)))

    // ---- phase B: 2-batch-deep counted-vmcnt pipeline, all named float2.
    vf2 a0, a1, a2, a3, a4, a5;   // batch 0
    vf2 b0v, b1v, b2v, b3v, b4v, b5v;   // batch 1
    vf2 c0, c1, c2, c3, c4, c5;   // batch 2
    vf2 d0, d1, d2, d3, d4, d5;   // batch 3
    float r00, r01, r02, r10, r11, r12, r20, r21, r22, r30, r31, r32;

#define BLEND(SX, SY, V0, V1, V2, V3, V4, V5, R0, R1, R2) {                    \
    const float wx_ = (SX) - (float)min((int)(SX), IMG_W - 2);                 \
    const float wy_ = (SY) - (float)min((int)(SY), IMG_H - 2);                 \
    R0 = bilin(wx_, wy_, V0, V1);                                              \
    R1 = bilin(wx_, wy_, V2, V3);                                              \
    R2 = bilin(wx_, wy_, V4, V5); }

    LOAD6(PBASE(0, sx0, sy0), a0, a1, a2, a3, a4, a5);
    LOAD6(PBASE(1, sx1, sy1), b0v, b1v, b2v, b3v, b4v, b5v);
    WAIT6(6, a0, a1, a2, a3, a4, a5);
    BLEND(sx0, sy0, a0, a1, a2, a3, a4, a5, r00, r01, r02);
    LOAD6(PBASE(2, sx2, sy2), c0, c1, c2, c3, c4, c5);
    WAIT6(6, b0v, b1v, b2v, b3v, b4v, b5v);
    BLEND(sx1, sy1, b0v, b1v, b2v, b3v, b4v, b5v, r10, r11, r12);
    LOAD6(PBASE(3, sx3, sy3), d0, d1, d2, d3, d4, d5);
    WAIT6(6, c0, c1, c2, c3, c4, c5);
    BLEND(sx2, sy2, c0, c1, c2, c3, c4, c5, r20, r21, r22);
    WAIT6(0, d0, d1, d2, d3, d4, d5);
    BLEND(sx3, sy3, d0, d1, d2, d3, d4, d5, r30, r31, r32);
#undef BLEND
#undef PBASE

    // ---- phase C: all 12 NT stores at the end (nothing waits on them).
    float* o0 = outb;
    float* o1 = outb + img_stride;
    float* o2 = outb + 2 * img_stride;
    float* o3 = outb + 3 * img_stride;
    __builtin_nontemporal_store(r00, o0);
    __builtin_nontemporal_store(r01, o0 + PLANE);
    __builtin_nontemporal_store(r02, o0 + 2 * PLANE);
    __builtin_nontemporal_store(r10, o1);
    __builtin_nontemporal_store(r11, o1 + PLANE);
    __builtin_nontemporal_store(r12, o1 + 2 * PLANE);
    __builtin_nontemporal_store(r20, o2);
    __builtin_nontemporal_store(r21, o2 + PLANE);
    __builtin_nontemporal_store(r22, o2 + 2 * PLANE);
    __builtin_nontemporal_store(r30, o3);
    __builtin_nontemporal_store(r31, o3 + PLANE);
    __builtin_nontemporal_store(r32, o3 + 2 * PLANE);
}

extern "C" void kernel_launch(void* const* d_in, const int* in_sizes, int n_in,
                              void* d_out, int out_size, void* d_ws, size_t ws_size,
                              hipStream_t stream) {
    const float* cloth = (const float*)d_in[0];
    const float* theta = (const float*)d_in[1];
    float* out = (float*)d_out;

    tps_warp_kernel<<<dim3(NWG), dim3(256), 0, stream>>>(cloth, theta, out);
}

// Round 13
// 35.181 us; speedup vs baseline: 1.1025x; 1.0358x over previous
//
#include <hip/hip_runtime.h>

constexpr int GRID_SZ = 5;
constexpr int N_CTRL  = 25;
constexpr int IMG_H   = 256;
constexpr int IMG_W   = 192;
constexpr int BATCH   = 64;
constexpr int BCHUNK  = 2;    // batches per thread; 4 sequential phases per XCD
constexpr int PLANE   = IMG_H * IMG_W;
constexpr int PIX_BLOCKS = PLANE / 256;             // 192
constexpr int NWG = PIX_BLOCKS * (BATCH / BCHUNK);  // 6144
constexpr float RBF_SCALE = 10.0f;
constexpr float OFF_SCALE = 0.3f;

typedef float vf2 __attribute__((ext_vector_type(2)));

__device__ __forceinline__ float bilin(float wx, float wy, vf2 r0, vf2 r1) {
    const float top = fmaf(wx, r0[1] - r0[0], r0[0]);
    const float bot = fmaf(wx, r1[1] - r1[0], r1[0]);
    return fmaf(wy, bot - top, top);
}

// 6 volatile gather loads for one batch: 3 channel-pointers, row-pair via
// offset:768 (= IMG_W floats). Volatile asm: cannot be deleted/reordered/sunk.
#define LOAD6(PBASE, VA0, VA1, VB0, VB1, VC0, VC1) do {                        \
    const float* p0_ = (PBASE);                                                \
    const float* p1_ = p0_ + PLANE;                                            \
    const float* p2_ = p1_ + PLANE;                                            \
    asm volatile("global_load_dwordx2 %0, %1, off"            : "=v"(VA0) : "v"(p0_)); \
    asm volatile("global_load_dwordx2 %0, %1, off offset:768" : "=v"(VA1) : "v"(p0_)); \
    asm volatile("global_load_dwordx2 %0, %1, off"            : "=v"(VB0) : "v"(p1_)); \
    asm volatile("global_load_dwordx2 %0, %1, off offset:768" : "=v"(VB1) : "v"(p1_)); \
    asm volatile("global_load_dwordx2 %0, %1, off"            : "=v"(VC0) : "v"(p2_)); \
    asm volatile("global_load_dwordx2 %0, %1, off offset:768" : "=v"(VC1) : "v"(p2_)); \
} while (0)

// Counted wait that PINS one batch's values (inputs AND outputs): its loads
// must precede, its blends must follow. T4: never drain to 0 until the end.
#define WAIT6(N, V0, V1, V2, V3, V4, V5)                                       \
    asm volatile("s_waitcnt vmcnt(" #N ")"                                     \
                 : "+v"(V0), "+v"(V1), "+v"(V2), "+v"(V3), "+v"(V4), "+v"(V5))

__global__ __launch_bounds__(256, 4) void tps_warp_kernel(
    const float* __restrict__ cloth,   // (64,3,256,192)
    const float* __restrict__ theta,   // (64,50)
    float* __restrict__ out)           // (64,3,256,192)
{
    // XCD swizzle with 4 SEQUENTIAL PHASES per XCD: XCD k handles 2-image
    // chunks {4k..4k+3} one after another. Instantaneous gather footprint
    // ~1.2-2.4 MB per XCD < 4 MiB private L2 (R12 straddled 2 phases at
    // 2.4-4.7 MB -> marginal residency; this is the L2-latency experiment).
    const int flat = blockIdx.x;
    const int xcd  = flat & 7;
    const int w    = flat >> 3;          // [0, 768) per XCD, dispatched in order
    const int pb   = w % PIX_BLOCKS;
    const int ph   = w / PIX_BLOCKS;     // phase 0..3, temporally sequential
    const int b0   = (xcd * 4 + ph) * BCHUNK;

    const int pix = pb * 256 + threadIdx.x;
    const int hh = pix / IMG_W;
    const int ww = pix - hh * IMG_W;
    const float mx = -1.0f + (2.0f / (IMG_W - 1)) * (float)ww;
    const float my = -1.0f + (2.0f / (IMG_H - 1)) * (float)hh;

    // Separable RBF basis — all named scalars (aggregates risk demotion).
#define RB(d) __expf(-(d) * (d) * RBF_SCALE)
    const float ex0 = RB(mx + 0.90f), ex1 = RB(mx + 0.45f), ex2 = RB(mx),
                ex3 = RB(mx - 0.45f), ex4 = RB(mx - 0.90f);
    const float ey0 = RB(my + 0.90f), ey1 = RB(my + 0.45f), ey2 = RB(my),
                ey3 = RB(my - 0.45f), ey4 = RB(my - 0.90f);
#undef RB

    // ---- phase A: 2 batches' offset accumulation, named accumulators.
    const float* t0 = theta + (size_t)(b0 + 0) * (2 * N_CTRL);
    const float* t1 = theta + (size_t)(b0 + 1) * (2 * N_CTRL);
    float ox0 = 0, oy0 = 0, ox1 = 0, oy1 = 0;
#define TERM(n, EX, EY) {                                                      \
    const float w_ = OFF_SCALE * (EX) * (EY);                                  \
    ox0 = fmaf(t0[2*(n)], w_, ox0); oy0 = fmaf(t0[2*(n)+1], w_, oy0);          \
    ox1 = fmaf(t1[2*(n)], w_, ox1); oy1 = fmaf(t1[2*(n)+1], w_, oy1); }
    TERM( 0, ex0, ey0) TERM( 1, ex1, ey0) TERM( 2, ex2, ey0) TERM( 3, ex3, ey0) TERM( 4, ex4, ey0)
    TERM( 5, ex0, ey1) TERM( 6, ex1, ey1) TERM( 7, ex2, ey1) TERM( 8, ex3, ey1) TERM( 9, ex4, ey1)
    TERM(10, ex0, ey2) TERM(11, ex1, ey2) TERM(12, ex2, ey2) TERM(13, ex3, ey2) TERM(14, ex4, ey2)
    TERM(15, ex0, ey3) TERM(16, ex1, ey3) TERM(17, ex2, ey3) TERM(18, ex3, ey3) TERM(19, ex4, ey3)
    TERM(20, ex0, ey4) TERM(21, ex1, ey4) TERM(22, ex2, ey4) TERM(23, ex3, ey4) TERM(24, ex4, ey4)
#undef TERM

#define COORD(OX, OY, SX, SY)                                                  \
    const float SX = (fminf(fmaxf(mx + (OX), -1.0f), 1.0f) + 1.0f) * (0.5f * (float)(IMG_W - 1)); \
    const float SY = (fminf(fmaxf(my + (OY), -1.0f), 1.0f) + 1.0f) * (0.5f * (float)(IMG_H - 1));
    COORD(ox0, oy0, sx0, sy0)
    COORD(ox1, oy1, sx1, sy1)
#undef COORD

    const size_t img_stride = (size_t)3 * PLANE;
    const float* imgb = cloth + (size_t)b0 * img_stride;
    float*       outb = out   + (size_t)b0 * img_stride + pix;

#define PBASE(B, SX, SY) (imgb + (size_t)(B) * img_stride +                    \
    (size_t)(min((int)(SY), IMG_H - 2) * IMG_W + min((int)(SX), IMG_W - 2)))

    // ---- phase B: depth-12 pipeline (both batches fully in flight; only
    // 24 VGPRs of load data), counted waits pin each batch's consumes.
    vf2 a0, a1, a2, a3, a4, a5;        // batch 0
    vf2 b0v, b1v, b2v, b3v, b4v, b5v;  // batch 1
    float r00, r01, r02, r10, r11, r12;

#define BLEND(SX, SY, V0, V1, V2, V3, V4, V5, R0, R1, R2) {                    \
    const float wx_ = (SX) - (float)min((int)(SX), IMG_W - 2);                 \
    const float wy_ = (SY) - (float)min((int)(SY), IMG_H - 2);                 \
    R0 = bilin(wx_, wy_, V0, V1);                                              \
    R1 = bilin(wx_, wy_, V2, V3);                                              \
    R2 = bilin(wx_, wy_, V4, V5); }

    LOAD6(PBASE(0, sx0, sy0), a0, a1, a2, a3, a4, a5);
    LOAD6(PBASE(1, sx1, sy1), b0v, b1v, b2v, b3v, b4v, b5v);
    WAIT6(6, a0, a1, a2, a3, a4, a5);
    BLEND(sx0, sy0, a0, a1, a2, a3, a4, a5, r00, r01, r02);
    WAIT6(0, b0v, b1v, b2v, b3v, b4v, b5v);
    BLEND(sx1, sy1, b0v, b1v, b2v, b3v, b4v, b5v, r10, r11, r12);
#undef BLEND
#undef PBASE

    // ---- phase C: 6 NT stores at the end (nothing waits on them).
    float* o0 = outb;
    float* o1 = outb + img_stride;
    __builtin_nontemporal_store(r00, o0);
    __builtin_nontemporal_store(r01, o0 + PLANE);
    __builtin_nontemporal_store(r02, o0 + 2 * PLANE);
    __builtin_nontemporal_store(r10, o1);
    __builtin_nontemporal_store(r11, o1 + PLANE);
    __builtin_nontemporal_store(r12, o1 + 2 * PLANE);
}

extern "C" void kernel_launch(void* const* d_in, const int* in_sizes, int n_in,
                              void* d_out, int out_size, void* d_ws, size_t ws_size,
                              hipStream_t stream) {
    const float* cloth = (const float*)d_in[0];
    const float* theta = (const float*)d_in[1];
    float* out = (float*)d_out;

    tps_warp_kernel<<<dim3(NWG), dim3(256), 0, stream>>>(cloth, theta, out);
}